// Round 1
// baseline (710.643 us; speedup 1.0000x reference)
//
#include <hip/hip_runtime.h>
#include <math.h>

#define TOK 18432
#define EMB 512
#define NH 8
#define HD_ 64
#define TT 8
#define HH 48
#define WW 48

// ---------------- RoPE cos/sin tables: rows 0..7 = t-axis, 8..55 = h-axis, 56..103 = w-axis
__global__ void fill_tabs(float2* __restrict__ tabs) {
    int idx = blockIdx.x * 256 + threadIdx.x;
    if (idx >= 104 * 10) return;
    int row = idx / 10, j = idx % 10;
    float base = fmaf((float)j, 127.0f / 9.0f, 1.0f) * 3.14159265358979323846f;
    float pos;
    if (row < 8)       pos = fmaf((float)row,        2.0f / 7.0f,  -1.0f);
    else if (row < 56) pos = fmaf((float)(row - 8),  2.0f / 47.0f, -1.0f);
    else               pos = fmaf((float)(row - 56), 2.0f / 47.0f, -1.0f);
    float f = pos * base;
    tabs[idx] = make_float2(cosf(f), sinf(f));
}

// ---------------- fp32 GEMM: C[M,N] = A[M,K] * B[N,K]^T (both K-contiguous)
#define BM 64
#define BN 128
#define BK 32
__global__ __launch_bounds__(256) void gemm_bt(const float* __restrict__ A,
                                               const float* __restrict__ B,
                                               float* __restrict__ C,
                                               int M, int N, int K) {
    __shared__ float As[BK][BM + 4];   // stride 68 floats (16B aligned)
    __shared__ float Bs[BK][BN + 4];   // stride 132 floats (16B aligned)
    int tid = threadIdx.x;
    int bm = blockIdx.y * BM;
    int bn = blockIdx.x * BN;
    int tx = tid & 15, ty = tid >> 4;  // n0 = tx*8, m0 = ty*4
    float acc[4][8];
#pragma unroll
    for (int i = 0; i < 4; ++i)
#pragma unroll
        for (int j = 0; j < 8; ++j) acc[i][j] = 0.f;

    for (int k0 = 0; k0 < K; k0 += BK) {
        // stage A tile (64x32), transposed into As[k][m]
#pragma unroll
        for (int it = 0; it < 2; ++it) {
            int idx = tid + it * 256;
            int r = idx >> 3, c4 = idx & 7;
            float4 v = *(const float4*)&A[(size_t)(bm + r) * K + k0 + c4 * 4];
            As[c4 * 4 + 0][r] = v.x; As[c4 * 4 + 1][r] = v.y;
            As[c4 * 4 + 2][r] = v.z; As[c4 * 4 + 3][r] = v.w;
        }
        // stage B tile (128x32), transposed into Bs[k][n]
#pragma unroll
        for (int it = 0; it < 4; ++it) {
            int idx = tid + it * 256;
            int r = idx >> 3, c4 = idx & 7;
            float4 v = *(const float4*)&B[(size_t)(bn + r) * K + k0 + c4 * 4];
            Bs[c4 * 4 + 0][r] = v.x; Bs[c4 * 4 + 1][r] = v.y;
            Bs[c4 * 4 + 2][r] = v.z; Bs[c4 * 4 + 3][r] = v.w;
        }
        __syncthreads();
#pragma unroll
        for (int k = 0; k < BK; ++k) {
            float4 a  = *(const float4*)&As[k][ty * 4];
            float4 b0 = *(const float4*)&Bs[k][tx * 8];
            float4 b1 = *(const float4*)&Bs[k][tx * 8 + 4];
            float av[4] = {a.x, a.y, a.z, a.w};
            float bv[8] = {b0.x, b0.y, b0.z, b0.w, b1.x, b1.y, b1.z, b1.w};
#pragma unroll
            for (int i = 0; i < 4; ++i)
#pragma unroll
                for (int j = 0; j < 8; ++j)
                    acc[i][j] = fmaf(av[i], bv[j], acc[i][j]);
        }
        __syncthreads();
    }
#pragma unroll
    for (int i = 0; i < 4; ++i) {
        float4 v0 = {acc[i][0], acc[i][1], acc[i][2], acc[i][3]};
        float4 v1 = {acc[i][4], acc[i][5], acc[i][6], acc[i][7]};
        size_t off = (size_t)(bm + ty * 4 + i) * N + bn + tx * 8;
        *(float4*)&C[off] = v0;
        *(float4*)&C[off + 4] = v1;
    }
}

// ---------------- fused RMSnorm + interleaved axial RoPE on q,k (in-place on qkv)
__global__ __launch_bounds__(256) void norm_rope(float* __restrict__ qkv,
                                                 const float2* __restrict__ tabs,
                                                 const float* __restrict__ qw,
                                                 const float* __restrict__ kw) {
    int token = blockIdx.x;
    int lane = threadIdx.x & 63;
    int wave = threadIdx.x >> 6;
    int t  = token / (HH * WW);
    int rem = token % (HH * WW);
    int xx = rem / WW;
    int yy = rem % WW;

    float2 cs = make_float2(1.f, 0.f);
    if (lane < 60) {
        int p = lane >> 1;  // pair index 0..29
        int tr;
        if (p < 10)      tr = t * 10 + p;
        else if (p < 20) tr = (8 + xx) * 10 + (p - 10);
        else             tr = (56 + yy) * 10 + (p - 20);
        cs = tabs[tr];
    }
#pragma unroll
    for (int v = 0; v < 4; ++v) {
        int vec = wave * 4 + v;       // 0..15
        int head = vec >> 1;
        int qk = vec & 1;             // 0 = q, 1 = k
        float* base = qkv + (size_t)token * 1536 + head * 192 + qk * 64;
        float x = base[lane];
        float ss = x * x;
#pragma unroll
        for (int o = 32; o; o >>= 1) ss += __shfl_xor(ss, o);
        float scale = rsqrtf(ss * (1.0f / 64.0f) + 1e-6f);
        float w = qk ? kw[lane] : qw[lane];
        float xn = x * scale * w;
        float partner = __shfl_xor(xn, 1);
        float r = xn;
        if (lane < 60) {
            // out[2i] = x[2i]*c - x[2i+1]*s ; out[2i+1] = x[2i+1]*c + x[2i]*s
            r = (lane & 1) ? fmaf(xn, cs.x,  partner * cs.y)
                           : fmaf(xn, cs.x, -partner * cs.y);
        }
        base[lane] = r;
    }
}

// ---------------- neighborhood attention: one block per (spatial pos, head), 8 time-queries
__global__ __launch_bounds__(256) void attn_kern(const float* __restrict__ qkv,
                                                 float* __restrict__ o) {
    __shared__ float Ks[72][68];
    __shared__ float Vs[72][68];
    __shared__ float Qs[8][68];
    __shared__ float Ss[8][76];
    int sp = blockIdx.x;
    int head = blockIdx.y;
    int xx = sp / WW, yy = sp % WW;
    int bx = min(max(xx - 1, 0), HH - 3);
    int by = min(max(yy - 1, 0), WW - 3);
    int tid = threadIdx.x;

    // stage K,V (72 rows x 64)
    for (int idx = tid; idx < 72 * 16; idx += 256) {
        int kk = idx >> 4, c = idx & 15;
        int s = kk / 9, r2 = kk % 9;
        int i = r2 / 3, j = r2 % 3;
        size_t tok = ((size_t)s * HH + (bx + i)) * WW + (by + j);
        const float* kp = qkv + tok * 1536 + head * 192 + 64 + c * 4;
        float4 kv = *(const float4*)kp;
        float4 vv = *(const float4*)(kp + 64);
        *(float4*)&Ks[kk][c * 4] = kv;
        *(float4*)&Vs[kk][c * 4] = vv;
    }
    // stage Q (8 rows x 64)
    for (int idx = tid; idx < 8 * 16; idx += 256) {
        int tq = idx >> 4, c = idx & 15;
        size_t tok = ((size_t)tq * HH + xx) * WW + yy;
        float4 qv = *(const float4*)(qkv + tok * 1536 + head * 192 + c * 4);
        *(float4*)&Qs[tq][c * 4] = qv;
    }
    __syncthreads();

    // scores: 8 t x 72 keys
    for (int e = tid; e < 576; e += 256) {
        int tq = e & 7, kk = e >> 3;
        float acc = 0.f;
#pragma unroll
        for (int c = 0; c < 16; ++c) {
            float4 q4 = *(const float4*)&Qs[tq][c * 4];
            float4 k4 = *(const float4*)&Ks[kk][c * 4];
            acc = fmaf(q4.x, k4.x, acc); acc = fmaf(q4.y, k4.y, acc);
            acc = fmaf(q4.z, k4.z, acc); acc = fmaf(q4.w, k4.w, acc);
        }
        Ss[tq][kk] = acc * 0.125f;   // HD^-0.5
    }
    __syncthreads();

    // softmax over 72, wave-parallel (wave handles t = wave, wave+4)
    int lane = tid & 63, wave = tid >> 6;
    for (int tq = wave; tq < 8; tq += 4) {
        float a = Ss[tq][lane];
        float b = (lane < 8) ? Ss[tq][64 + lane] : -1e30f;
        float m = fmaxf(a, b);
#pragma unroll
        for (int o2 = 32; o2; o2 >>= 1) m = fmaxf(m, __shfl_xor(m, o2));
        float ea = expf(a - m);
        float eb = (lane < 8) ? expf(b - m) : 0.f;
        float s = ea + eb;
#pragma unroll
        for (int o2 = 32; o2; o2 >>= 1) s += __shfl_xor(s, o2);
        float inv = 1.0f / s;
        Ss[tq][lane] = ea * inv;
        if (lane < 8) Ss[tq][64 + lane] = eb * inv;
    }
    __syncthreads();

    // PV: threads 0..127, thread = (t, 4-wide d-group)
    if (tid < 128) {
        int tq = tid >> 4, g = tid & 15;
        float4 acc = {0.f, 0.f, 0.f, 0.f};
#pragma unroll 8
        for (int kk = 0; kk < 72; ++kk) {
            float sv = Ss[tq][kk];
            float4 v4 = *(const float4*)&Vs[kk][g * 4];
            acc.x = fmaf(sv, v4.x, acc.x);
            acc.y = fmaf(sv, v4.y, acc.y);
            acc.z = fmaf(sv, v4.z, acc.z);
            acc.w = fmaf(sv, v4.w, acc.w);
        }
        size_t tok = ((size_t)tq * HH + xx) * WW + yy;
        *(float4*)&o[tok * EMB + head * HD_ + g * 4] = acc;
    }
}

extern "C" void kernel_launch(void* const* d_in, const int* in_sizes, int n_in,
                              void* d_out, int out_size, void* d_ws, size_t ws_size,
                              hipStream_t stream) {
    const float* x     = (const float*)d_in[0];
    const float* w_qkv = (const float*)d_in[1];
    const float* w_out = (const float*)d_in[2];
    const float* qnw   = (const float*)d_in[3];
    const float* knw   = (const float*)d_in[4];
    float* out = (float*)d_out;
    float* ws  = (float*)d_ws;

    const size_t QKV  = (size_t)TOK * 1536;   // 28,311,552 floats
    const size_t TABS = 4096;                 // room for 1040 float2
    const size_t OBUF = (size_t)TOK * EMB;    // 9,437,184 floats

    float* qkv  = ws;
    float* tabs = ws + QKV;
    bool big = ws_size >= (QKV + TABS + OBUF + 1024) * sizeof(float);
    float* obuf = big ? (ws + QKV + TABS) : out;   // attention output
    float* c2   = big ? out : ws;                  // final GEMM output

    fill_tabs<<<5, 256, 0, stream>>>((float2*)tabs);
    gemm_bt<<<dim3(1536 / BN, TOK / BM), 256, 0, stream>>>(x, w_qkv, qkv, TOK, 1536, EMB);
    norm_rope<<<TOK, 256, 0, stream>>>(qkv, (const float2*)tabs, qnw, knw);
    attn_kern<<<dim3(HH * WW, NH), 256, 0, stream>>>(qkv, obuf);
    gemm_bt<<<dim3(EMB / BN, TOK / BM), 256, 0, stream>>>(obuf, w_out, c2, TOK, EMB, EMB);
    if (!big) {
        hipMemcpyAsync(out, c2, OBUF * sizeof(float), hipMemcpyDeviceToDevice, stream);
    }
}

// Round 2
// 283.078 us; speedup vs baseline: 2.5104x; 2.5104x over previous
//
#include <hip/hip_runtime.h>
#include <hip/hip_bf16.h>
#include <math.h>

#define TOK 18432
#define EMB 512
#define NH 8
#define HD_ 64
#define HH 48
#define WW 48

typedef __attribute__((ext_vector_type(8))) short  s16x8;
typedef __attribute__((ext_vector_type(4))) float  f32x4;

__device__ __forceinline__ ushort f2bf(float x) {
    __hip_bfloat16 b = __float2bfloat16(x);
    return *(ushort*)&b;
}
__device__ __forceinline__ float bf2f(ushort u) {
    __hip_bfloat16 b = *(__hip_bfloat16*)&u;
    return __bfloat162float(b);
}

// async global->LDS, 16B per lane. LDS dest rule: wave-uniform base + lane*16.
__device__ __forceinline__ void gload16(const void* g, void* l) {
    __builtin_amdgcn_global_load_lds((const __attribute__((address_space(1))) void*)g,
                                     (__attribute__((address_space(3))) void*)l,
                                     16, 0, 0);
}

__device__ __forceinline__ f32x4 mfma_bf16(s16x8 a, s16x8 b, f32x4 c) {
    asm("v_mfma_f32_16x16x32_bf16 %0, %1, %2, %0" : "+v"(c) : "v"(a), "v"(b));
    return c;
}

// ---------------- RoPE cos/sin tables: rows 0..7 = t, 8..55 = h, 56..103 = w
__global__ void fill_tabs(float2* __restrict__ tabs) {
    int idx = blockIdx.x * 256 + threadIdx.x;
    if (idx >= 104 * 10) return;
    int row = idx / 10, j = idx % 10;
    float base = fmaf((float)j, 127.0f / 9.0f, 1.0f) * 3.14159265358979323846f;
    float pos;
    if (row < 8)       pos = fmaf((float)row,        2.0f / 7.0f,  -1.0f);
    else if (row < 56) pos = fmaf((float)(row - 8),  2.0f / 47.0f, -1.0f);
    else               pos = fmaf((float)(row - 56), 2.0f / 47.0f, -1.0f);
    float f = pos * base;
    tabs[idx] = make_float2(cosf(f), sinf(f));
}

// ---------------- fp32 -> bf16 (hi only)
__global__ __launch_bounds__(256) void conv_hi(const float* __restrict__ src,
                                               ushort* __restrict__ dst, int n4) {
    int i = blockIdx.x * 256 + threadIdx.x;
    if (i >= n4) return;
    float4 v = ((const float4*)src)[i];
    ushort4 h = {f2bf(v.x), f2bf(v.y), f2bf(v.z), f2bf(v.w)};
    ((ushort4*)dst)[i] = h;
}

// ---------------- fp32 -> bf16 hi + lo (split)
__global__ __launch_bounds__(256) void conv_hilo(const float* __restrict__ src,
                                                 ushort* __restrict__ hi,
                                                 ushort* __restrict__ lo, int n4) {
    int i = blockIdx.x * 256 + threadIdx.x;
    if (i >= n4) return;
    float4 v = ((const float4*)src)[i];
    ushort4 h = {f2bf(v.x), f2bf(v.y), f2bf(v.z), f2bf(v.w)};
    ushort4 l = {f2bf(v.x - bf2f(h.x)), f2bf(v.y - bf2f(h.y)),
                 f2bf(v.z - bf2f(h.z)), f2bf(v.w - bf2f(h.w))};
    ((ushort4*)hi)[i] = h;
    ((ushort4*)lo)[i] = l;
}

// ---------------- bf16 MFMA GEMM: C[M,N] = A[M,K] * B[N,K]^T, fp32 out.
// SPLIT=1: 3-term hi/lo split (A,B each hi+lo; lo*lo dropped).
// 128x128 tile, BK=32, 4 waves, each wave 64x64 via 4x4 16x16x32 frags.
template<int SPLIT>
__global__ __launch_bounds__(256) void gemm_mfma(const ushort* __restrict__ Ah,
                                                 const ushort* __restrict__ Al,
                                                 const ushort* __restrict__ Bh,
                                                 const ushort* __restrict__ Bl,
                                                 float* __restrict__ C,
                                                 int N, int K, int nbx) {
    __shared__ __align__(16) ushort As[1 + SPLIT][128 * 32];
    __shared__ __align__(16) ushort Bs[1 + SPLIT][128 * 32];
    int nwg = gridDim.x;
    int bid = blockIdx.x;
    int cpx = nwg >> 3;                       // grid % 8 == 0 guaranteed
    int swz = (bid & 7) * cpx + (bid >> 3);   // XCD-aware swizzle (bijective)
    int bm = (swz / nbx) * 128, bn = (swz % nbx) * 128;
    int tid = threadIdx.x;
    int lane = tid & 63, wave = tid >> 6;
    int wr = wave >> 1, wc = wave & 1;
    int fr = lane & 15, kg = lane >> 4;

    f32x4 acc[4][4];
#pragma unroll
    for (int m = 0; m < 4; ++m)
#pragma unroll
        for (int n = 0; n < 4; ++n) acc[m][n] = (f32x4){0.f, 0.f, 0.f, 0.f};

    for (int k0 = 0; k0 < K; k0 += 32) {
        // stage 128x32 tiles: flat f in [0,512), 16B per f; LDS linear = f*16B
#pragma unroll
        for (int it = 0; it < 2; ++it) {
            int f = it * 256 + tid;
            int row = f >> 2, ch = f & 3;
            size_t goA = (size_t)(bm + row) * K + k0 + ch * 8;
            size_t goB = (size_t)(bn + row) * K + k0 + ch * 8;
            gload16(Ah + goA, &As[0][f * 8]);
            gload16(Bh + goB, &Bs[0][f * 8]);
            if (SPLIT) {
                gload16(Al + goA, &As[1][f * 8]);
                gload16(Bl + goB, &Bs[1][f * 8]);
            }
        }
        __syncthreads();

        s16x8 bh[4], bl[4];
#pragma unroll
        for (int n = 0; n < 4; ++n) {
            int rb = (wc * 64 + n * 16 + fr) * 32 + kg * 8;
            bh[n] = *(const s16x8*)&Bs[0][rb];
            if (SPLIT) bl[n] = *(const s16x8*)&Bs[1][rb];
        }
#pragma unroll
        for (int m = 0; m < 4; ++m) {
            int ra = (wr * 64 + m * 16 + fr) * 32 + kg * 8;
            s16x8 ah = *(const s16x8*)&As[0][ra];
            s16x8 al;
            if (SPLIT) al = *(const s16x8*)&As[1][ra];
#pragma unroll
            for (int n = 0; n < 4; ++n) {
                acc[m][n] = mfma_bf16(ah, bh[n], acc[m][n]);
                if (SPLIT) {
                    acc[m][n] = mfma_bf16(ah, bl[n], acc[m][n]);
                    acc[m][n] = mfma_bf16(al, bh[n], acc[m][n]);
                }
            }
        }
        __syncthreads();
    }
    // epilogue: C/D layout col=lane&15, row=(lane>>4)*4+i
#pragma unroll
    for (int m = 0; m < 4; ++m) {
        int row0 = bm + wr * 64 + m * 16 + kg * 4;
#pragma unroll
        for (int n = 0; n < 4; ++n) {
            int col = bn + wc * 64 + n * 16 + fr;
#pragma unroll
            for (int i = 0; i < 4; ++i)
                C[(size_t)(row0 + i) * N + col] = acc[m][n][i];
        }
    }
}

// ---------------- fused RMSnorm + interleaved axial RoPE on q,k (in-place, fp32)
__global__ __launch_bounds__(256) void norm_rope(float* __restrict__ qkv,
                                                 const float2* __restrict__ tabs,
                                                 const float* __restrict__ qw,
                                                 const float* __restrict__ kw) {
    int token = blockIdx.x;
    int lane = threadIdx.x & 63;
    int wave = threadIdx.x >> 6;
    int t  = token / (HH * WW);
    int rem = token % (HH * WW);
    int xx = rem / WW;
    int yy = rem % WW;

    float2 cs = make_float2(1.f, 0.f);
    if (lane < 60) {
        int p = lane >> 1;
        int tr;
        if (p < 10)      tr = t * 10 + p;
        else if (p < 20) tr = (8 + xx) * 10 + (p - 10);
        else             tr = (56 + yy) * 10 + (p - 20);
        cs = tabs[tr];
    }
#pragma unroll
    for (int v = 0; v < 4; ++v) {
        int vec = wave * 4 + v;
        int head = vec >> 1;
        int qk = vec & 1;
        float* base = qkv + (size_t)token * 1536 + head * 192 + qk * 64;
        float x = base[lane];
        float ss = x * x;
#pragma unroll
        for (int o = 32; o; o >>= 1) ss += __shfl_xor(ss, o);
        float scale = rsqrtf(ss * (1.0f / 64.0f) + 1e-6f);
        float w = qk ? kw[lane] : qw[lane];
        float xn = x * scale * w;
        float partner = __shfl_xor(xn, 1);
        float r = xn;
        if (lane < 60) {
            r = (lane & 1) ? fmaf(xn, cs.x,  partner * cs.y)
                           : fmaf(xn, cs.x, -partner * cs.y);
        }
        base[lane] = r;
    }
}

// ---------------- neighborhood attention; writes hi/lo bf16 output
__global__ __launch_bounds__(256) void attn_kern(const float* __restrict__ qkv,
                                                 ushort* __restrict__ ohi,
                                                 ushort* __restrict__ olo) {
    __shared__ float Ks[72][68];
    __shared__ float Vs[72][68];
    __shared__ float Qs[8][68];
    __shared__ float Ss[8][76];
    int sp = blockIdx.x;
    int head = blockIdx.y;
    int xx = sp / WW, yy = sp % WW;
    int bx = min(max(xx - 1, 0), HH - 3);
    int by = min(max(yy - 1, 0), WW - 3);
    int tid = threadIdx.x;

    for (int idx = tid; idx < 72 * 16; idx += 256) {
        int kk = idx >> 4, c = idx & 15;
        int s = kk / 9, r2 = kk % 9;
        int i = r2 / 3, j = r2 % 3;
        size_t tok = ((size_t)s * HH + (bx + i)) * WW + (by + j);
        const float* kp = qkv + tok * 1536 + head * 192 + 64 + c * 4;
        float4 kv = *(const float4*)kp;
        float4 vv = *(const float4*)(kp + 64);
        *(float4*)&Ks[kk][c * 4] = kv;
        *(float4*)&Vs[kk][c * 4] = vv;
    }
    for (int idx = tid; idx < 8 * 16; idx += 256) {
        int tq = idx >> 4, c = idx & 15;
        size_t tok = ((size_t)tq * HH + xx) * WW + yy;
        float4 qv = *(const float4*)(qkv + tok * 1536 + head * 192 + c * 4);
        *(float4*)&Qs[tq][c * 4] = qv;
    }
    __syncthreads();

    for (int e = tid; e < 576; e += 256) {
        int tq = e & 7, kk = e >> 3;
        float acc = 0.f;
#pragma unroll
        for (int c = 0; c < 16; ++c) {
            float4 q4 = *(const float4*)&Qs[tq][c * 4];
            float4 k4 = *(const float4*)&Ks[kk][c * 4];
            acc = fmaf(q4.x, k4.x, acc); acc = fmaf(q4.y, k4.y, acc);
            acc = fmaf(q4.z, k4.z, acc); acc = fmaf(q4.w, k4.w, acc);
        }
        Ss[tq][kk] = acc * 0.125f;
    }
    __syncthreads();

    int lane = tid & 63, wave = tid >> 6;
    for (int tq = wave; tq < 8; tq += 4) {
        float a = Ss[tq][lane];
        float b = (lane < 8) ? Ss[tq][64 + lane] : -1e30f;
        float m = fmaxf(a, b);
#pragma unroll
        for (int o2 = 32; o2; o2 >>= 1) m = fmaxf(m, __shfl_xor(m, o2));
        float ea = expf(a - m);
        float eb = (lane < 8) ? expf(b - m) : 0.f;
        float s = ea + eb;
#pragma unroll
        for (int o2 = 32; o2; o2 >>= 1) s += __shfl_xor(s, o2);
        float inv = 1.0f / s;
        Ss[tq][lane] = ea * inv;
        if (lane < 8) Ss[tq][64 + lane] = eb * inv;
    }
    __syncthreads();

    if (tid < 128) {
        int tq = tid >> 4, g = tid & 15;
        float4 acc = {0.f, 0.f, 0.f, 0.f};
#pragma unroll 8
        for (int kk = 0; kk < 72; ++kk) {
            float sv = Ss[tq][kk];
            float4 v4 = *(const float4*)&Vs[kk][g * 4];
            acc.x = fmaf(sv, v4.x, acc.x);
            acc.y = fmaf(sv, v4.y, acc.y);
            acc.z = fmaf(sv, v4.z, acc.z);
            acc.w = fmaf(sv, v4.w, acc.w);
        }
        size_t ob = (((size_t)tq * HH + xx) * WW + yy) * EMB + head * HD_ + g * 4;
        ushort4 hv = {f2bf(acc.x), f2bf(acc.y), f2bf(acc.z), f2bf(acc.w)};
        ushort4 lv = {f2bf(acc.x - bf2f(hv.x)), f2bf(acc.y - bf2f(hv.y)),
                      f2bf(acc.z - bf2f(hv.z)), f2bf(acc.w - bf2f(hv.w))};
        *(ushort4*)&ohi[ob] = hv;
        *(ushort4*)&olo[ob] = lv;
    }
}

extern "C" void kernel_launch(void* const* d_in, const int* in_sizes, int n_in,
                              void* d_out, int out_size, void* d_ws, size_t ws_size,
                              hipStream_t stream) {
    const float* x     = (const float*)d_in[0];
    const float* w_qkv = (const float*)d_in[1];
    const float* w_out = (const float*)d_in[2];
    const float* qnw   = (const float*)d_in[3];
    const float* knw   = (const float*)d_in[4];
    float* out = (float*)d_out;
    char*  ws  = (char*)d_ws;

    const size_t QKV_B  = (size_t)TOK * 1536 * 4;   // 113,246,208
    const size_t TABS_B = 16384;
    const size_t XHI_B  = (size_t)TOK * 512 * 2;    // 18,874,368
    const size_t WQ_B   = (size_t)1536 * 512 * 2;   // 1,572,864
    const size_t WO_B   = (size_t)512 * 512 * 2;    // 524,288
    const size_t O_B    = (size_t)TOK * 512 * 2;    // 18,874,368
    const size_t OUT_B  = (size_t)TOK * 512 * 4;    // 37,748,736

    float*  qkv  = (float*)ws;
    float2* tabs = (float2*)(ws + QKV_B);

    size_t need_fast = QKV_B + TABS_B + XHI_B + WQ_B + 2 * WO_B + 2 * O_B;
    bool fast = ws_size >= need_fast;

    ushort *xhi, *wqhi, *wohi, *wolo, *ohi, *olo;
    float* c2;
    if (fast) {
        xhi  = (ushort*)(ws + QKV_B + TABS_B);
        wqhi = xhi + (size_t)TOK * 512;
        wohi = wqhi + (size_t)1536 * 512;
        wolo = wohi + (size_t)512 * 512;
        ohi  = wolo + (size_t)512 * 512;
        olo  = ohi + (size_t)TOK * 512;
        c2   = out;
    } else {
        // low-ws tier: xhi/wqhi live in d_out (dead before attn overwrites),
        // ohi/olo then reuse d_out; final C goes to ws (qkv dead) + d2d copy.
        wohi = (ushort*)(ws + QKV_B + TABS_B);
        wolo = wohi + (size_t)512 * 512;
        xhi  = (ushort*)d_out;
        wqhi = xhi + (size_t)TOK * 512;
        ohi  = (ushort*)d_out;
        olo  = ohi + (size_t)TOK * 512;
        c2   = (float*)ws;
    }

    fill_tabs<<<5, 256, 0, stream>>>(tabs);
    conv_hi<<<(TOK * 512 / 4 + 255) / 256, 256, 0, stream>>>(x, xhi, TOK * 512 / 4);
    conv_hi<<<(1536 * 512 / 4 + 255) / 256, 256, 0, stream>>>(w_qkv, wqhi, 1536 * 512 / 4);
    conv_hilo<<<(512 * 512 / 4 + 255) / 256, 256, 0, stream>>>(w_out, wohi, wolo, 512 * 512 / 4);

    // qkv = x @ w_qkv^T  (plain bf16, fp32 accum)
    gemm_mfma<0><<<(TOK / 128) * (1536 / 128), 256, 0, stream>>>(
        xhi, nullptr, wqhi, nullptr, qkv, 1536, 512, 1536 / 128);
    norm_rope<<<TOK, 256, 0, stream>>>(qkv, tabs, qnw, knw);
    attn_kern<<<dim3(HH * WW, NH), 256, 0, stream>>>(qkv, ohi, olo);
    // out = o @ w_out^T  (3-term split bf16 ~= fp32)
    gemm_mfma<1><<<(TOK / 128) * (512 / 128), 256, 0, stream>>>(
        ohi, olo, wohi, wolo, c2, 512, 512, 512 / 128);
    if (!fast) {
        hipMemcpyAsync(out, c2, OUT_B, hipMemcpyDeviceToDevice, stream);
    }
}

// Round 4
// 215.363 us; speedup vs baseline: 3.2997x; 1.3144x over previous
//
#include <hip/hip_runtime.h>
#include <hip/hip_bf16.h>
#include <math.h>

#define TOK 18432
#define EMB 512
#define NH 8
#define HD_ 64
#define HH 48
#define WW 48

typedef __attribute__((ext_vector_type(8))) __bf16 bf16x8;
typedef __attribute__((ext_vector_type(4))) float  f32x4;

__device__ __forceinline__ ushort f2bf(float x) {
    __hip_bfloat16 b = __float2bfloat16(x);
    return *(ushort*)&b;
}
__device__ __forceinline__ float bf2f(ushort u) {
    __hip_bfloat16 b = *(__hip_bfloat16*)&u;
    return __bfloat162float(b);
}

// async global->LDS, 16B per lane. LDS dest = wave-uniform base + lane*16 (linear).
__device__ __forceinline__ void gload16(const void* g, void* l) {
    __builtin_amdgcn_global_load_lds((const __attribute__((address_space(1))) void*)g,
                                     (__attribute__((address_space(3))) void*)l,
                                     16, 0, 0);
}

// official builtin so the compiler inserts MFMA hazard nops (inline asm is NOT
// seen by the hazard recognizer -> stale VALU reads of the D registers).
__device__ __forceinline__ f32x4 mfma_bf16(bf16x8 a, bf16x8 b, f32x4 c) {
    return __builtin_amdgcn_mfma_f32_16x16x32_bf16(a, b, c, 0, 0, 0);
}

// ---------------- RoPE cos/sin tables: rows 0..7 = t, 8..55 = h, 56..103 = w
__global__ void fill_tabs(float2* __restrict__ tabs) {
    int idx = blockIdx.x * 256 + threadIdx.x;
    if (idx >= 104 * 10) return;
    int row = idx / 10, j = idx % 10;
    float base = fmaf((float)j, 127.0f / 9.0f, 1.0f) * 3.14159265358979323846f;
    float pos;
    if (row < 8)       pos = fmaf((float)row,        2.0f / 7.0f,  -1.0f);
    else if (row < 56) pos = fmaf((float)(row - 8),  2.0f / 47.0f, -1.0f);
    else               pos = fmaf((float)(row - 56), 2.0f / 47.0f, -1.0f);
    float f = pos * base;
    tabs[idx] = make_float2(cosf(f), sinf(f));
}

// ---------------- fp32 -> bf16 (hi only)
__global__ __launch_bounds__(256) void conv_hi(const float* __restrict__ src,
                                               ushort* __restrict__ dst, int n4) {
    int i = blockIdx.x * 256 + threadIdx.x;
    if (i >= n4) return;
    float4 v = ((const float4*)src)[i];
    ushort4 h = {f2bf(v.x), f2bf(v.y), f2bf(v.z), f2bf(v.w)};
    ((ushort4*)dst)[i] = h;
}

// ---------------- fp32 -> bf16 hi + lo (split)
__global__ __launch_bounds__(256) void conv_hilo(const float* __restrict__ src,
                                                 ushort* __restrict__ hi,
                                                 ushort* __restrict__ lo, int n4) {
    int i = blockIdx.x * 256 + threadIdx.x;
    if (i >= n4) return;
    float4 v = ((const float4*)src)[i];
    ushort4 h = {f2bf(v.x), f2bf(v.y), f2bf(v.z), f2bf(v.w)};
    ushort4 l = {f2bf(v.x - bf2f(h.x)), f2bf(v.y - bf2f(h.y)),
                 f2bf(v.z - bf2f(h.z)), f2bf(v.w - bf2f(h.w))};
    ((ushort4*)hi)[i] = h;
    ((ushort4*)lo)[i] = l;
}

// ---------------- bf16 MFMA GEMM: C[M,N] = A[M,K] * B[N,K]^T, fp32 out.
template<int SPLIT>
__global__ __launch_bounds__(256) void gemm_mfma(const ushort* __restrict__ Ah,
                                                 const ushort* __restrict__ Al,
                                                 const ushort* __restrict__ Bh,
                                                 const ushort* __restrict__ Bl,
                                                 float* __restrict__ C,
                                                 int N, int K, int nbx) {
    __shared__ __align__(16) ushort As[1 + SPLIT][128 * 32];
    __shared__ __align__(16) ushort Bs[1 + SPLIT][128 * 32];
    int nwg = gridDim.x;
    int bid = blockIdx.x;
    int cpx = nwg >> 3;
    int swz = (bid & 7) * cpx + (bid >> 3);
    int bm = (swz / nbx) * 128, bn = (swz % nbx) * 128;
    int tid = threadIdx.x;
    int lane = tid & 63, wave = tid >> 6;
    int wr = wave >> 1, wc = wave & 1;
    int fr = lane & 15, kg = lane >> 4;

    f32x4 acc[4][4];
#pragma unroll
    for (int m = 0; m < 4; ++m)
#pragma unroll
        for (int n = 0; n < 4; ++n) acc[m][n] = (f32x4){0.f, 0.f, 0.f, 0.f};

    for (int k0 = 0; k0 < K; k0 += 32) {
#pragma unroll
        for (int it = 0; it < 2; ++it) {
            int f = it * 256 + tid;
            int row = f >> 2, ch = f & 3;
            size_t goA = (size_t)(bm + row) * K + k0 + ch * 8;
            size_t goB = (size_t)(bn + row) * K + k0 + ch * 8;
            gload16(Ah + goA, &As[0][f * 8]);
            gload16(Bh + goB, &Bs[0][f * 8]);
            if (SPLIT) {
                gload16(Al + goA, &As[1][f * 8]);
                gload16(Bl + goB, &Bs[1][f * 8]);
            }
        }
        __syncthreads();

        bf16x8 bh[4], bl[4];
#pragma unroll
        for (int n = 0; n < 4; ++n) {
            int rb = (wc * 64 + n * 16 + fr) * 32 + kg * 8;
            bh[n] = *(const bf16x8*)&Bs[0][rb];
            if (SPLIT) bl[n] = *(const bf16x8*)&Bs[1][rb];
        }
#pragma unroll
        for (int m = 0; m < 4; ++m) {
            int ra = (wr * 64 + m * 16 + fr) * 32 + kg * 8;
            bf16x8 ah = *(const bf16x8*)&As[0][ra];
            bf16x8 al;
            if (SPLIT) al = *(const bf16x8*)&As[1][ra];
#pragma unroll
            for (int n = 0; n < 4; ++n) {
                acc[m][n] = mfma_bf16(ah, bh[n], acc[m][n]);
                if (SPLIT) {
                    acc[m][n] = mfma_bf16(ah, bl[n], acc[m][n]);
                    acc[m][n] = mfma_bf16(al, bh[n], acc[m][n]);
                }
            }
        }
        __syncthreads();
    }
#pragma unroll
    for (int m = 0; m < 4; ++m) {
        int row0 = bm + wr * 64 + m * 16 + kg * 4;
#pragma unroll
        for (int n = 0; n < 4; ++n) {
            int col = bn + wc * 64 + n * 16 + fr;
#pragma unroll
            for (int i = 0; i < 4; ++i)
                C[(size_t)(row0 + i) * N + col] = acc[m][n][i];
        }
    }
}

// ---------------- fused RMSnorm + RoPE, emits bf16 q/k/v buffers [tok][head*64+d]
__global__ __launch_bounds__(256) void norm_rope_v2(const float* __restrict__ qkv,
                                                    const float2* __restrict__ tabs,
                                                    const float* __restrict__ qw,
                                                    const float* __restrict__ kw,
                                                    ushort* __restrict__ qbf,
                                                    ushort* __restrict__ kbf,
                                                    ushort* __restrict__ vbf) {
    int token = blockIdx.x;
    int lane = threadIdx.x & 63;
    int w = threadIdx.x >> 6;
    int t  = token / (HH * WW);
    int rem = token % (HH * WW);
    int xx = rem / WW;
    int yy = rem % WW;

    float2 cs = make_float2(1.f, 0.f);
    if (lane < 60) {
        int p = lane >> 1;
        int tr;
        if (p < 10)      tr = t * 10 + p;
        else if (p < 20) tr = (8 + xx) * 10 + (p - 10);
        else             tr = (56 + yy) * 10 + (p - 20);
        cs = tabs[tr];
    }
    float qwl = qw[lane], kwl = kw[lane];
#pragma unroll
    for (int hh = 0; hh < 2; ++hh) {
        int h = w * 2 + hh;
        const float* base = qkv + (size_t)token * 1536 + h * 192;
        size_t ob = (size_t)token * 512 + h * 64 + lane;
#pragma unroll
        for (int qk = 0; qk < 2; ++qk) {
            float x = base[qk * 64 + lane];
            float ss = x * x;
#pragma unroll
            for (int o = 32; o; o >>= 1) ss += __shfl_xor(ss, o);
            float scale = rsqrtf(ss * (1.0f / 64.0f) + 1e-6f);
            float xn = x * scale * (qk ? kwl : qwl);
            float partner = __shfl_xor(xn, 1);
            float r = xn;
            if (lane < 60) {
                r = (lane & 1) ? fmaf(xn, cs.x,  partner * cs.y)
                               : fmaf(xn, cs.x, -partner * cs.y);
            }
            (qk ? kbf : qbf)[ob] = f2bf(r);
        }
        vbf[ob] = f2bf(base[128 + lane]);
    }
}

// ---------------- MFMA neighborhood attention: block = (2x2 patch, head)
// 32 queries (8t x 4sp) x 128 keys (8t x 4x4 window), masked softmax.
__global__ __launch_bounds__(256) void attn_mfma(const ushort* __restrict__ qbf,
                                                 const ushort* __restrict__ kbf,
                                                 const ushort* __restrict__ vbf,
                                                 ushort* __restrict__ ohi,
                                                 ushort* __restrict__ olo) {
    __shared__ __align__(16) char smem[53888];
    constexpr int Q_OFF = 0;       // [32][64] bf16, stride 128B, xor ((row&7)<<4)
    constexpr int K_OFF = 4096;    // [128][64] bf16, stride 128B, xor
    constexpr int P_OFF = 4096;    // alias over K after QK: [32][128] bf16, stride 256B, xor
    constexpr int V_OFF = 20480;   // [64 d][128 k] bf16, stride 256B, xor
    constexpr int S_OFF = 36864;   // [32][132] f32
    constexpr int I_OFF = 53760;   // [32] f32 invsum

    int patch = blockIdx.x, head = blockIdx.y;
    int bi = patch / 24, bj = patch % 24;
    int x0 = bi * 2, y0 = bj * 2;
    int ubx = min(max(x0 - 1, 0), 44), uby = min(max(y0 - 1, 0), 44);
    int tid = threadIdx.x, lane = tid & 63, w = tid >> 6;
    int fr = lane & 15, kg = lane >> 4;

    // ---- stage Q (gload16, pre-swizzled source column)
    {
        int f = w * 64 + lane;
        int row = f >> 3, sp = f & 7, sl = sp ^ (row & 7);
        int t = row >> 2, px = (row >> 1) & 1, py = row & 1;
        size_t tok = ((size_t)(t * HH + x0 + px)) * WW + (y0 + py);
        gload16(qbf + tok * 512 + head * 64 + sl * 8, smem + Q_OFF + f * 16);
    }
    // ---- stage K (4 gloads per wave)
#pragma unroll
    for (int it = 0; it < 4; ++it) {
        int f = it * 256 + w * 64 + lane;
        int kk = f >> 3, sp = f & 7, sl = sp ^ (kk & 7);
        int s = kk >> 4, ki = (kk >> 2) & 3, kj = kk & 3;
        size_t tok = ((size_t)(s * HH + ubx + ki)) * WW + (uby + kj);
        gload16(kbf + tok * 512 + head * 64 + sl * 8, smem + K_OFF + f * 16);
    }
    // ---- stage V transposed (VGPR path, swizzled b16 writes)
#pragma unroll
    for (int it = 0; it < 8; ++it) {
        int g = it * 256 + tid;
        int kk = g >> 4, c = g & 15;
        int s = kk >> 4, ki = (kk >> 2) & 3, kj = kk & 3;
        size_t tok = ((size_t)(s * HH + ubx + ki)) * WW + (uby + kj);
        ushort4 v4 = *(const ushort4*)(vbf + tok * 512 + head * 64 + c * 4);
        ushort vv[4] = {v4.x, v4.y, v4.z, v4.w};
#pragma unroll
        for (int dd = 0; dd < 4; ++dd) {
            int d = c * 4 + dd;
            *(ushort*)(smem + V_OFF + d * 256 + ((kk * 2) ^ ((d & 7) << 4))) = vv[dd];
        }
    }
    __syncthreads();

    // ---- QK^T: wave w owns n-tiles {2w, 2w+1}
    bf16x8 qa[2][2];
#pragma unroll
    for (int m = 0; m < 2; ++m)
#pragma unroll
        for (int ks = 0; ks < 2; ++ks)
            qa[m][ks] = *(const bf16x8*)(smem + Q_OFF + (m * 16 + fr) * 128 +
                                         ((ks * 64 + kg * 16) ^ ((fr & 7) << 4)));
    f32x4 sc[2][2];
#pragma unroll
    for (int m = 0; m < 2; ++m)
#pragma unroll
        for (int n2 = 0; n2 < 2; ++n2) sc[m][n2] = (f32x4){0.f, 0.f, 0.f, 0.f};
#pragma unroll
    for (int n2 = 0; n2 < 2; ++n2) {
        int nrow = (w * 2 + n2) * 16 + fr;
#pragma unroll
        for (int ks = 0; ks < 2; ++ks) {
            bf16x8 b = *(const bf16x8*)(smem + K_OFF + nrow * 128 +
                                        ((ks * 64 + kg * 16) ^ ((fr & 7) << 4)));
#pragma unroll
            for (int m = 0; m < 2; ++m) sc[m][n2] = mfma_bf16(qa[m][ks], b, sc[m][n2]);
        }
    }
    float* S = (float*)(smem + S_OFF);
#pragma unroll
    for (int m = 0; m < 2; ++m)
#pragma unroll
        for (int n2 = 0; n2 < 2; ++n2)
#pragma unroll
            for (int i = 0; i < 4; ++i)
                S[(m * 16 + kg * 4 + i) * 132 + (w * 2 + n2) * 16 + fr] = sc[m][n2][i] * 0.125f;
    __syncthreads();

    // ---- masked softmax (wave w: rows w*8..w*8+7), P = exp(s-max) bf16, deferred 1/sum
    float* INV = (float*)(smem + I_OFF);
    {
        int ki = (lane >> 2) & 3, kj = lane & 3;   // same for lane and lane+64
        for (int rr = 0; rr < 8; ++rr) {
            int r = w * 8 + rr;
            int xq = x0 + ((r >> 1) & 1), yq = y0 + (r & 1);
            int lox = min(max(xq - 1, 0), 45) - ubx;
            int loy = min(max(yq - 1, 0), 45) - uby;
            bool valid = ((unsigned)(ki - lox) <= 2u) && ((unsigned)(kj - loy) <= 2u);
            float v0 = valid ? S[r * 132 + lane]      : -1e30f;
            float v1 = valid ? S[r * 132 + 64 + lane] : -1e30f;
            float mx = fmaxf(v0, v1);
#pragma unroll
            for (int o = 32; o; o >>= 1) mx = fmaxf(mx, __shfl_xor(mx, o));
            float p0 = valid ? __expf(v0 - mx) : 0.f;
            float p1 = valid ? __expf(v1 - mx) : 0.f;
            float sm = p0 + p1;
#pragma unroll
            for (int o = 32; o; o >>= 1) sm += __shfl_xor(sm, o);
            int sw = (r & 7) << 4;
            *(ushort*)(smem + P_OFF + r * 256 + ((lane * 2) ^ sw))        = f2bf(p0);
            *(ushort*)(smem + P_OFF + r * 256 + (((lane + 64) * 2) ^ sw)) = f2bf(p1);
            if (lane == 0) INV[r] = 1.0f / sm;
        }
    }
    __syncthreads();

    // ---- PV: wave w owns d-tile w (16 dims)
    f32x4 ov[2];
    ov[0] = (f32x4){0.f, 0.f, 0.f, 0.f};
    ov[1] = (f32x4){0.f, 0.f, 0.f, 0.f};
#pragma unroll
    for (int ks = 0; ks < 4; ++ks) {
        bf16x8 b = *(const bf16x8*)(smem + V_OFF + (w * 16 + fr) * 256 +
                                    ((ks * 64 + kg * 16) ^ ((fr & 7) << 4)));
#pragma unroll
        for (int m = 0; m < 2; ++m) {
            bf16x8 a = *(const bf16x8*)(smem + P_OFF + (m * 16 + fr) * 256 +
                                        ((ks * 64 + kg * 16) ^ ((fr & 7) << 4)));
            ov[m] = mfma_bf16(a, b, ov[m]);
        }
    }
    // ---- epilogue: out hi/lo bf16
#pragma unroll
    for (int m = 0; m < 2; ++m)
#pragma unroll
        for (int i = 0; i < 4; ++i) {
            int q = m * 16 + kg * 4 + i;
            float val = ov[m][i] * INV[q];
            int t = q >> 2, px = (q >> 1) & 1, py = q & 1;
            size_t tok = ((size_t)(t * HH + x0 + px)) * WW + (y0 + py);
            size_t ob = tok * 512 + head * 64 + w * 16 + fr;
            ushort h = f2bf(val);
            ohi[ob] = h;
            olo[ob] = f2bf(val - bf2f(h));
        }
}

extern "C" void kernel_launch(void* const* d_in, const int* in_sizes, int n_in,
                              void* d_out, int out_size, void* d_ws, size_t ws_size,
                              hipStream_t stream) {
    const float* x     = (const float*)d_in[0];
    const float* w_qkv = (const float*)d_in[1];
    const float* w_out = (const float*)d_in[2];
    const float* qnw   = (const float*)d_in[3];
    const float* knw   = (const float*)d_in[4];
    float* out = (float*)d_out;
    char*  ws  = (char*)d_ws;

    const size_t QKV_B  = (size_t)TOK * 1536 * 4;   // 113,246,208
    const size_t TABS_B = 16384;
    const size_t XHI_B  = (size_t)TOK * 512 * 2;    // 18,874,368
    const size_t WQ_B   = (size_t)1536 * 512 * 2;
    const size_t WO_B   = (size_t)512 * 512 * 2;
    const size_t QBF_B  = (size_t)TOK * 512 * 2;
    const size_t OUT_B  = (size_t)TOK * 512 * 4;

    float*  qkv  = (float*)ws;
    float2* tabs = (float2*)(ws + QKV_B);
    // ohi/olo alias qkv region (qkv dead after norm_rope_v2)
    ushort* ohi = (ushort*)ws;
    ushort* olo = (ushort*)(ws + QBF_B);

    size_t need_fast = QKV_B + TABS_B + XHI_B + WQ_B + 2 * WO_B + 2 * QBF_B;
    bool fast = ws_size >= need_fast;

    ushort *xhi, *wqhi, *wohi, *wolo, *qbf, *kbf, *vbf;
    float* c2;
    if (fast) {
        xhi  = (ushort*)(ws + QKV_B + TABS_B);
        vbf  = xhi;                                  // alias: xhi dead after gemm1
        wqhi = (ushort*)(ws + QKV_B + TABS_B + XHI_B);
        wohi = wqhi + (size_t)1536 * 512;
        wolo = wohi + (size_t)512 * 512;
        qbf  = wolo + (size_t)512 * 512;
        kbf  = qbf + (size_t)TOK * 512;
        c2   = out;
    } else {
        // xhi + wqhi live in d_out (dead before attn); vbf aliases xhi there.
        xhi  = (ushort*)d_out;
        vbf  = xhi;
        wqhi = xhi + (size_t)TOK * 512;
        wohi = (ushort*)(ws + QKV_B + TABS_B);
        wolo = wohi + (size_t)512 * 512;
        qbf  = wolo + (size_t)512 * 512;
        kbf  = qbf + (size_t)TOK * 512;
        c2   = (float*)(ws + 50 * 1024 * 1024);      // inside dead qkv, past ohi/olo
    }

    fill_tabs<<<5, 256, 0, stream>>>(tabs);
    conv_hi<<<(TOK * 512 / 4 + 255) / 256, 256, 0, stream>>>(x, xhi, TOK * 512 / 4);
    conv_hi<<<(1536 * 512 / 4 + 255) / 256, 256, 0, stream>>>(w_qkv, wqhi, 1536 * 512 / 4);
    conv_hilo<<<(512 * 512 / 4 + 255) / 256, 256, 0, stream>>>(w_out, wohi, wolo, 512 * 512 / 4);

    gemm_mfma<0><<<(TOK / 128) * (1536 / 128), 256, 0, stream>>>(
        xhi, nullptr, wqhi, nullptr, qkv, 1536, 512, 1536 / 128);
    norm_rope_v2<<<TOK, 256, 0, stream>>>(qkv, tabs, qnw, knw, qbf, kbf, vbf);
    attn_mfma<<<dim3(576, NH), 256, 0, stream>>>(qbf, kbf, vbf, ohi, olo);
    gemm_mfma<1><<<(TOK / 128) * (512 / 128), 256, 0, stream>>>(
        ohi, olo, wohi, wolo, c2, 512, 512, 512 / 128);
    if (!fast) {
        hipMemcpyAsync(out, c2, OUT_B, hipMemcpyDeviceToDevice, stream);
    }
}

// Round 5
// 171.884 us; speedup vs baseline: 4.1344x; 1.2530x over previous
//
#include <hip/hip_runtime.h>
#include <hip/hip_bf16.h>
#include <math.h>

#define TOK 18432
#define EMB 512
#define NH 8
#define HD_ 64
#define HH 48
#define WW 48

typedef __attribute__((ext_vector_type(8))) __bf16 bf16x8;
typedef __attribute__((ext_vector_type(4))) float  f32x4;

__device__ __forceinline__ ushort f2bf(float x) {
    __hip_bfloat16 b = __float2bfloat16(x);
    return *(ushort*)&b;
}
__device__ __forceinline__ float bf2f(ushort u) {
    __hip_bfloat16 b = *(__hip_bfloat16*)&u;
    return __bfloat162float(b);
}

// async global->LDS, 16B per lane. LDS dest = wave-uniform base + lane*16 (linear).
__device__ __forceinline__ void gload16(const void* g, void* l) {
    __builtin_amdgcn_global_load_lds((const __attribute__((address_space(1))) void*)g,
                                     (__attribute__((address_space(3))) void*)l,
                                     16, 0, 0);
}

// builtin (NOT inline asm) so the hazard recognizer inserts MFMA->VALU nops.
__device__ __forceinline__ f32x4 mfma_bf16(bf16x8 a, bf16x8 b, f32x4 c) {
    return __builtin_amdgcn_mfma_f32_16x16x32_bf16(a, b, c, 0, 0, 0);
}

// ---------------- RoPE cos/sin tables: rows 0..7 = t, 8..55 = h, 56..103 = w
__global__ void fill_tabs(float2* __restrict__ tabs) {
    int idx = blockIdx.x * 256 + threadIdx.x;
    if (idx >= 104 * 10) return;
    int row = idx / 10, j = idx % 10;
    float base = fmaf((float)j, 127.0f / 9.0f, 1.0f) * 3.14159265358979323846f;
    float pos;
    if (row < 8)       pos = fmaf((float)row,        2.0f / 7.0f,  -1.0f);
    else if (row < 56) pos = fmaf((float)(row - 8),  2.0f / 47.0f, -1.0f);
    else               pos = fmaf((float)(row - 56), 2.0f / 47.0f, -1.0f);
    float f = pos * base;
    tabs[idx] = make_float2(cosf(f), sinf(f));
}

// ---------------- fp32 -> bf16 (hi only)
__global__ __launch_bounds__(256) void conv_hi(const float* __restrict__ src,
                                               ushort* __restrict__ dst, int n4) {
    int i = blockIdx.x * 256 + threadIdx.x;
    if (i >= n4) return;
    float4 v = ((const float4*)src)[i];
    ushort4 h = {f2bf(v.x), f2bf(v.y), f2bf(v.z), f2bf(v.w)};
    ((ushort4*)dst)[i] = h;
}

// ---------------- bf16 MFMA GEMM: C[M,N] = A[M,K] * B[N,K]^T, fp32 out.
// SPLIT=1: 2-term A-split (Ahi*Bh + Alo*Bh) -- A error fully kept, B hi-only.
template<int SPLIT>
__global__ __launch_bounds__(256) void gemm_mfma(const ushort* __restrict__ Ah,
                                                 const ushort* __restrict__ Al,
                                                 const ushort* __restrict__ Bh,
                                                 float* __restrict__ C,
                                                 int N, int K, int nbx) {
    __shared__ __align__(16) ushort As[1 + SPLIT][128 * 32];
    __shared__ __align__(16) ushort Bs[128 * 32];
    int nwg = gridDim.x;
    int bid = blockIdx.x;
    int cpx = nwg >> 3;
    int swz = (bid & 7) * cpx + (bid >> 3);
    int bm = (swz / nbx) * 128, bn = (swz % nbx) * 128;
    int tid = threadIdx.x;
    int lane = tid & 63, wave = tid >> 6;
    int wr = wave >> 1, wc = wave & 1;
    int fr = lane & 15, kg = lane >> 4;

    f32x4 acc[4][4];
#pragma unroll
    for (int m = 0; m < 4; ++m)
#pragma unroll
        for (int n = 0; n < 4; ++n) acc[m][n] = (f32x4){0.f, 0.f, 0.f, 0.f};

    for (int k0 = 0; k0 < K; k0 += 32) {
#pragma unroll
        for (int it = 0; it < 2; ++it) {
            int f = it * 256 + tid;
            int row = f >> 2, ch = f & 3;
            size_t goA = (size_t)(bm + row) * K + k0 + ch * 8;
            size_t goB = (size_t)(bn + row) * K + k0 + ch * 8;
            gload16(Ah + goA, &As[0][f * 8]);
            gload16(Bh + goB, &Bs[f * 8]);
            if (SPLIT) gload16(Al + goA, &As[1][f * 8]);
        }
        __syncthreads();

        bf16x8 bh[4];
#pragma unroll
        for (int n = 0; n < 4; ++n) {
            int rb = (wc * 64 + n * 16 + fr) * 32 + kg * 8;
            bh[n] = *(const bf16x8*)&Bs[rb];
        }
#pragma unroll
        for (int m = 0; m < 4; ++m) {
            int ra = (wr * 64 + m * 16 + fr) * 32 + kg * 8;
            bf16x8 ah = *(const bf16x8*)&As[0][ra];
            bf16x8 al;
            if (SPLIT) al = *(const bf16x8*)&As[1][ra];
#pragma unroll
            for (int n = 0; n < 4; ++n) {
                acc[m][n] = mfma_bf16(ah, bh[n], acc[m][n]);
                if (SPLIT) acc[m][n] = mfma_bf16(al, bh[n], acc[m][n]);
            }
        }
        __syncthreads();
    }
#pragma unroll
    for (int m = 0; m < 4; ++m) {
        int row0 = bm + wr * 64 + m * 16 + kg * 4;
#pragma unroll
        for (int n = 0; n < 4; ++n) {
            int col = bn + wc * 64 + n * 16 + fr;
#pragma unroll
            for (int i = 0; i < 4; ++i)
                C[(size_t)(row0 + i) * N + col] = acc[m][n][i];
        }
    }
}

// ---------------- fused RMSnorm + RoPE -> bf16 q/k/v; q pre-scaled by HD^-0.5
__global__ __launch_bounds__(256) void norm_rope_v2(const float* __restrict__ qkv,
                                                    const float2* __restrict__ tabs,
                                                    const float* __restrict__ qw,
                                                    const float* __restrict__ kw,
                                                    ushort* __restrict__ qbf,
                                                    ushort* __restrict__ kbf,
                                                    ushort* __restrict__ vbf) {
    int token = blockIdx.x;
    int lane = threadIdx.x & 63;
    int w = threadIdx.x >> 6;
    int t  = token / (HH * WW);
    int rem = token % (HH * WW);
    int xx = rem / WW;
    int yy = rem % WW;

    float2 cs = make_float2(1.f, 0.f);
    if (lane < 60) {
        int p = lane >> 1;
        int tr;
        if (p < 10)      tr = t * 10 + p;
        else if (p < 20) tr = (8 + xx) * 10 + (p - 10);
        else             tr = (56 + yy) * 10 + (p - 20);
        cs = tabs[tr];
    }
    float qwl = qw[lane], kwl = kw[lane];
#pragma unroll
    for (int hh = 0; hh < 2; ++hh) {
        int h = w * 2 + hh;
        const float* base = qkv + (size_t)token * 1536 + h * 192;
        size_t ob = (size_t)token * 512 + h * 64 + lane;
#pragma unroll
        for (int qk = 0; qk < 2; ++qk) {
            float x = base[qk * 64 + lane];
            float ss = x * x;
#pragma unroll
            for (int o = 32; o; o >>= 1) ss += __shfl_xor(ss, o);
            float scale = rsqrtf(ss * (1.0f / 64.0f) + 1e-6f);
            float xn = x * scale * (qk ? kwl : qwl);
            float partner = __shfl_xor(xn, 1);
            float r = xn;
            if (lane < 60) {
                r = (lane & 1) ? fmaf(xn, cs.x,  partner * cs.y)
                               : fmaf(xn, cs.x, -partner * cs.y);
            }
            if (!qk) r *= 0.125f;   // fold HD^-0.5 into q (exact pow2)
            (qk ? kbf : qbf)[ob] = f2bf(r);
        }
        vbf[ob] = f2bf(base[128 + lane]);
    }
}

// ---------------- MFMA neighborhood attention v3: swapped operands,
// in-register lane-local masked softmax. Block = (2x2 patch, head).
// 32 q (8t x 2x2) x 128 k (8t x 4x4 window).
__global__ __launch_bounds__(256) void attn_mfma(const ushort* __restrict__ qbf,
                                                 const ushort* __restrict__ kbf,
                                                 const ushort* __restrict__ vbf,
                                                 ushort* __restrict__ ohi,
                                                 ushort* __restrict__ olo) {
    __shared__ __align__(16) char smem[45056];
    constexpr int Q_OFF = 0;       // [32 q][64 d] bf16, 128B rows, slot16 ^= row&7
    constexpr int K_OFF = 4096;    // [128 k][64 d] bf16, 128B rows, slot16 ^= row&7
    constexpr int V_OFF = 20480;   // [64 d][128 k] bf16, 256B rows, slot16 ^= d&7
    constexpr int P_OFF = 36864;   // [32 q][128 k] bf16, 256B rows, slot16 ^= q&7

    int patch = blockIdx.x, head = blockIdx.y;
    int bi = patch / 24, bj = patch % 24;
    int x0 = bi * 2, y0 = bj * 2;
    int ubx = min(max(x0 - 1, 0), 44), uby = min(max(y0 - 1, 0), 44);
    int tid = threadIdx.x, lane = tid & 63, w = tid >> 6;
    int fr = lane & 15, kg = lane >> 4;

    // ---- stage Q (1 gload/thread, pre-swizzled source chunk)
    {
        int f = tid;
        int row = f >> 3, sp = f & 7, sl = sp ^ (row & 7);
        int t = row >> 2, px = (row >> 1) & 1, py = row & 1;
        size_t tok = ((size_t)(t * HH + x0 + px)) * WW + (y0 + py);
        gload16(qbf + tok * 512 + head * 64 + sl * 8, smem + Q_OFF + f * 16);
    }
    // ---- stage K (4 gloads/thread)
#pragma unroll
    for (int it = 0; it < 4; ++it) {
        int f = it * 256 + tid;
        int row = f >> 3, sp = f & 7, sl = sp ^ (row & 7);
        int s = row >> 4, ki = (row >> 2) & 3, kj = row & 3;
        size_t tok = ((size_t)(s * HH + ubx + ki)) * WW + (uby + kj);
        gload16(kbf + tok * 512 + head * 64 + sl * 8, smem + K_OFF + f * 16);
    }
    // ---- stage V^T: register 4x4 transpose, b64 swizzled writes
#pragma unroll
    for (int it = 0; it < 2; ++it) {
        int u = it * 256 + tid;
        int sk = u >> 4, dg = u & 15;
        int s = sk >> 2, ki = sk & 3;
        ushort4 rv[4];
#pragma unroll
        for (int kj = 0; kj < 4; ++kj) {
            size_t tok = ((size_t)(s * HH + ubx + ki)) * WW + (uby + kj);
            rv[kj] = *(const ushort4*)(vbf + tok * 512 + head * 64 + dg * 4);
        }
        const ushort* rr = (const ushort*)rv;   // rr[kj*4 + dd]
#pragma unroll
        for (int dd = 0; dd < 4; ++dd) {
            int d = dg * 4 + dd;
            ushort4 val = {rr[dd], rr[4 + dd], rr[8 + dd], rr[12 + dd]};
            *(ushort4*)(smem + V_OFF + d * 256 + ((sk * 8) ^ ((d & 7) << 4))) = val;
        }
    }
    __syncthreads();

    // ---- QK^T swapped (S^T = K * Q^T) + in-register masked softmax: waves 0,1
    if (w < 2) {
        int nt = w;                  // q-tile
        int q = nt * 16 + fr;        // q = t*4 + px*2 + py
        bf16x8 qb[2];
#pragma unroll
        for (int ks = 0; ks < 2; ++ks)
            qb[ks] = *(const bf16x8*)(smem + Q_OFF + q * 128 +
                                      ((ks * 64 + kg * 16) ^ ((fr & 7) << 4)));
        f32x4 sc[8];
#pragma unroll
        for (int m = 0; m < 8; ++m) sc[m] = (f32x4){0.f, 0.f, 0.f, 0.f};
#pragma unroll
        for (int m = 0; m < 8; ++m)
#pragma unroll
            for (int ks = 0; ks < 2; ++ks) {
                bf16x8 a = *(const bf16x8*)(smem + K_OFF + (m * 16 + fr) * 128 +
                                            ((ks * 64 + kg * 16) ^ ((fr & 7) << 4)));
                sc[m] = mfma_bf16(a, qb[ks], sc[m]);
            }
        // lane holds S[k = m*16 + kg*4 + i][q]: s=m, ki=kg, kj=i
        int xq = x0 + ((q >> 1) & 1), yq = y0 + (q & 1);
        int lox = min(max(xq - 1, 0), 45) - ubx;
        int loy = min(max(yq - 1, 0), 45) - uby;
        bool vki = ((unsigned)(kg - lox)) <= 2u;
        float mx = -1e30f;
        if (vki) {
#pragma unroll
            for (int m = 0; m < 8; ++m)
#pragma unroll
                for (int i = 0; i < 4; ++i)
                    if (((unsigned)(i - loy)) <= 2u) mx = fmaxf(mx, sc[m][i]);
        }
        mx = fmaxf(mx, __shfl_xor(mx, 16));
        mx = fmaxf(mx, __shfl_xor(mx, 32));
        float sum = 0.f;
#pragma unroll
        for (int m = 0; m < 8; ++m)
#pragma unroll
            for (int i = 0; i < 4; ++i) {
                bool v = vki && (((unsigned)(i - loy)) <= 2u);
                float e = v ? __expf(sc[m][i] - mx) : 0.f;
                sc[m][i] = e;
                sum += e;
            }
        sum += __shfl_xor(sum, 16);
        sum += __shfl_xor(sum, 32);
        float inv = 1.0f / sum;
#pragma unroll
        for (int m = 0; m < 8; ++m) {
            ushort4 pk = {f2bf(sc[m][0] * inv), f2bf(sc[m][1] * inv),
                          f2bf(sc[m][2] * inv), f2bf(sc[m][3] * inv)};
            *(ushort4*)(smem + P_OFF + q * 256 +
                        ((m * 32 + kg * 8) ^ ((q & 7) << 4))) = pk;
        }
    }
    __syncthreads();

    // ---- PV swapped (out^T = V^T * P^T): wave w owns d-tile w
    f32x4 ov[2];
    ov[0] = (f32x4){0.f, 0.f, 0.f, 0.f};
    ov[1] = (f32x4){0.f, 0.f, 0.f, 0.f};
#pragma unroll
    for (int kb = 0; kb < 4; ++kb) {
        bf16x8 a = *(const bf16x8*)(smem + V_OFF + (w * 16 + fr) * 256 +
                                    ((kb * 64 + kg * 16) ^ ((fr & 7) << 4)));
#pragma unroll
        for (int nt2 = 0; nt2 < 2; ++nt2) {
            bf16x8 b = *(const bf16x8*)(smem + P_OFF + (nt2 * 16 + fr) * 256 +
                                        ((kb * 64 + kg * 16) ^ ((fr & 7) << 4)));
            ov[nt2] = mfma_bf16(a, b, ov[nt2]);
        }
    }
    // ---- epilogue: lane holds out^T[d = w*16+kg*4+i][q = nt2*16+fr]
#pragma unroll
    for (int nt2 = 0; nt2 < 2; ++nt2) {
        int q = nt2 * 16 + fr;
        int t = q >> 2, px = (q >> 1) & 1, py = q & 1;
        size_t tok = ((size_t)(t * HH + x0 + px)) * WW + (y0 + py);
        size_t ob = tok * 512 + head * 64 + w * 16 + kg * 4;
        ushort4 hv = {f2bf(ov[nt2][0]), f2bf(ov[nt2][1]),
                      f2bf(ov[nt2][2]), f2bf(ov[nt2][3])};
        ushort4 lv = {f2bf(ov[nt2][0] - bf2f(hv.x)), f2bf(ov[nt2][1] - bf2f(hv.y)),
                      f2bf(ov[nt2][2] - bf2f(hv.z)), f2bf(ov[nt2][3] - bf2f(hv.w))};
        *(ushort4*)&ohi[ob] = hv;
        *(ushort4*)&olo[ob] = lv;
    }
}

extern "C" void kernel_launch(void* const* d_in, const int* in_sizes, int n_in,
                              void* d_out, int out_size, void* d_ws, size_t ws_size,
                              hipStream_t stream) {
    const float* x     = (const float*)d_in[0];
    const float* w_qkv = (const float*)d_in[1];
    const float* w_out = (const float*)d_in[2];
    const float* qnw   = (const float*)d_in[3];
    const float* knw   = (const float*)d_in[4];
    float* out = (float*)d_out;
    char*  ws  = (char*)d_ws;

    const size_t QKV_B  = (size_t)TOK * 1536 * 4;   // 113,246,208
    const size_t TABS_B = 16384;
    const size_t XHI_B  = (size_t)TOK * 512 * 2;    // 18,874,368
    const size_t WQ_B   = (size_t)1536 * 512 * 2;
    const size_t WO_B   = (size_t)512 * 512 * 2;
    const size_t QBF_B  = (size_t)TOK * 512 * 2;
    const size_t OUT_B  = (size_t)TOK * 512 * 4;

    float*  qkv  = (float*)ws;
    float2* tabs = (float2*)(ws + QKV_B);
    // ohi/olo alias qkv region (qkv dead after norm_rope_v2)
    ushort* ohi = (ushort*)ws;
    ushort* olo = (ushort*)(ws + QBF_B);

    size_t need_fast = QKV_B + TABS_B + XHI_B + WQ_B + WO_B + 2 * QBF_B;
    bool fast = ws_size >= need_fast;

    ushort *xhi, *wqhi, *wohi, *qbf, *kbf, *vbf;
    float* c2;
    if (fast) {
        xhi  = (ushort*)(ws + QKV_B + TABS_B);
        vbf  = xhi;                                  // alias: xhi dead after gemm1
        wqhi = (ushort*)(ws + QKV_B + TABS_B + XHI_B);
        wohi = wqhi + (size_t)1536 * 512;
        qbf  = wohi + (size_t)512 * 512;
        kbf  = qbf + (size_t)TOK * 512;
        c2   = out;
    } else {
        // xhi + wqhi live in d_out (dead before attn); vbf aliases xhi there.
        xhi  = (ushort*)d_out;
        vbf  = xhi;
        wqhi = xhi + (size_t)TOK * 512;
        wohi = (ushort*)(ws + QKV_B + TABS_B);
        qbf  = wohi + (size_t)512 * 512;
        kbf  = qbf + (size_t)TOK * 512;
        c2   = (float*)(ws + 50 * 1024 * 1024);      // inside dead qkv, past ohi/olo
    }

    fill_tabs<<<5, 256, 0, stream>>>(tabs);
    conv_hi<<<(TOK * 512 / 4 + 255) / 256, 256, 0, stream>>>(x, xhi, TOK * 512 / 4);
    conv_hi<<<(1536 * 512 / 4 + 255) / 256, 256, 0, stream>>>(w_qkv, wqhi, 1536 * 512 / 4);
    conv_hi<<<(512 * 512 / 4 + 255) / 256, 256, 0, stream>>>(w_out, wohi, 512 * 512 / 4);

    gemm_mfma<0><<<(TOK / 128) * (1536 / 128), 256, 0, stream>>>(
        xhi, nullptr, wqhi, qkv, 1536, 512, 1536 / 128);
    norm_rope_v2<<<TOK, 256, 0, stream>>>(qkv, tabs, qnw, knw, qbf, kbf, vbf);
    attn_mfma<<<dim3(576, NH), 256, 0, stream>>>(qbf, kbf, vbf, ohi, olo);
    gemm_mfma<1><<<(TOK / 128) * (512 / 128), 256, 0, stream>>>(
        ohi, olo, wohi, c2, 512, 512, 512 / 128);
    if (!fast) {
        hipMemcpyAsync(out, c2, OUT_B, hipMemcpyDeviceToDevice, stream);
    }
}

// Round 6
// 151.769 us; speedup vs baseline: 4.6824x; 1.1325x over previous
//
#include <hip/hip_runtime.h>
#include <hip/hip_bf16.h>
#include <math.h>

#define TOK 18432
#define EMB 512
#define NH 8
#define HD_ 64
#define HH 48
#define WW 48

typedef __attribute__((ext_vector_type(8))) __bf16 bf16x8;
typedef __attribute__((ext_vector_type(4))) float  f32x4;

__device__ __forceinline__ ushort f2bf(float x) {
    __hip_bfloat16 b = __float2bfloat16(x);
    return *(ushort*)&b;
}
__device__ __forceinline__ float bf2f(ushort u) {
    __hip_bfloat16 b = *(__hip_bfloat16*)&u;
    return __bfloat162float(b);
}

// async global->LDS, 16B per lane. LDS dest = wave-uniform base + lane*16 (linear).
__device__ __forceinline__ void gload16(const void* g, void* l) {
    __builtin_amdgcn_global_load_lds((const __attribute__((address_space(1))) void*)g,
                                     (__attribute__((address_space(3))) void*)l,
                                     16, 0, 0);
}

// builtin (NOT inline asm) so the hazard recognizer inserts MFMA->VALU nops.
__device__ __forceinline__ f32x4 mfma_bf16(bf16x8 a, bf16x8 b, f32x4 c) {
    return __builtin_amdgcn_mfma_f32_16x16x32_bf16(a, b, c, 0, 0, 0);
}

// ---------------- RoPE cos/sin tables: rows 0..7 = t, 8..55 = h, 56..103 = w
__global__ void fill_tabs(float2* __restrict__ tabs) {
    int idx = blockIdx.x * 256 + threadIdx.x;
    if (idx >= 104 * 10) return;
    int row = idx / 10, j = idx % 10;
    float base = fmaf((float)j, 127.0f / 9.0f, 1.0f) * 3.14159265358979323846f;
    float pos;
    if (row < 8)       pos = fmaf((float)row,        2.0f / 7.0f,  -1.0f);
    else if (row < 56) pos = fmaf((float)(row - 8),  2.0f / 47.0f, -1.0f);
    else               pos = fmaf((float)(row - 56), 2.0f / 47.0f, -1.0f);
    float f = pos * base;
    tabs[idx] = make_float2(cosf(f), sinf(f));
}

// ---------------- fp32 -> bf16 (hi only)
__global__ __launch_bounds__(256) void conv_hi(const float* __restrict__ src,
                                               ushort* __restrict__ dst, int n4) {
    int i = blockIdx.x * 256 + threadIdx.x;
    if (i >= n4) return;
    float4 v = ((const float4*)src)[i];
    ushort4 h = {f2bf(v.x), f2bf(v.y), f2bf(v.z), f2bf(v.w)};
    ((ushort4*)dst)[i] = h;
}

// ---------------- bf16 MFMA GEMM: C[M,N] = A[M,K] * B[N,K]^T.
// OUTBF=1: bf16 output, else fp32. 128x128 tile, BK=32, 4 waves.
template<int OUTBF>
__global__ __launch_bounds__(256) void gemm_mfma(const ushort* __restrict__ Ah,
                                                 const ushort* __restrict__ Bh,
                                                 void* __restrict__ Cv,
                                                 int N, int K, int nbx) {
    __shared__ __align__(16) ushort As[128 * 32];
    __shared__ __align__(16) ushort Bs[128 * 32];
    int nwg = gridDim.x;
    int bid = blockIdx.x;
    int cpx = nwg >> 3;                       // grid % 8 == 0 guaranteed
    int swz = (bid & 7) * cpx + (bid >> 3);   // XCD-aware swizzle (bijective)
    int bm = (swz / nbx) * 128, bn = (swz % nbx) * 128;
    int tid = threadIdx.x;
    int lane = tid & 63, wave = tid >> 6;
    int wr = wave >> 1, wc = wave & 1;
    int fr = lane & 15, kg = lane >> 4;

    f32x4 acc[4][4];
#pragma unroll
    for (int m = 0; m < 4; ++m)
#pragma unroll
        for (int n = 0; n < 4; ++n) acc[m][n] = (f32x4){0.f, 0.f, 0.f, 0.f};

    for (int k0 = 0; k0 < K; k0 += 32) {
#pragma unroll
        for (int it = 0; it < 2; ++it) {
            int f = it * 256 + tid;
            int row = f >> 2, ch = f & 3;
            size_t goA = (size_t)(bm + row) * K + k0 + ch * 8;
            size_t goB = (size_t)(bn + row) * K + k0 + ch * 8;
            gload16(Ah + goA, &As[f * 8]);
            gload16(Bh + goB, &Bs[f * 8]);
        }
        __syncthreads();

        bf16x8 bh[4];
#pragma unroll
        for (int n = 0; n < 4; ++n) {
            int rb = (wc * 64 + n * 16 + fr) * 32 + kg * 8;
            bh[n] = *(const bf16x8*)&Bs[rb];
        }
#pragma unroll
        for (int m = 0; m < 4; ++m) {
            int ra = (wr * 64 + m * 16 + fr) * 32 + kg * 8;
            bf16x8 ah = *(const bf16x8*)&As[ra];
#pragma unroll
            for (int n = 0; n < 4; ++n)
                acc[m][n] = mfma_bf16(ah, bh[n], acc[m][n]);
        }
        __syncthreads();
    }
    // epilogue: C/D layout col=lane&15, row=(lane>>4)*4+i
#pragma unroll
    for (int m = 0; m < 4; ++m) {
        int row0 = bm + wr * 64 + m * 16 + kg * 4;
#pragma unroll
        for (int n = 0; n < 4; ++n) {
            int col = bn + wc * 64 + n * 16 + fr;
#pragma unroll
            for (int i = 0; i < 4; ++i) {
                if (OUTBF)
                    ((ushort*)Cv)[(size_t)(row0 + i) * N + col] = f2bf(acc[m][n][i]);
                else
                    ((float*)Cv)[(size_t)(row0 + i) * N + col] = acc[m][n][i];
            }
        }
    }
}

// ---------------- fused RMSnorm + RoPE on bf16 qkv -> bf16 q,k buffers.
// v stays in-place in qkvb (read directly by attn). q pre-scaled by HD^-0.5.
__global__ __launch_bounds__(256) void norm_rope_v3(const ushort* __restrict__ qkvb,
                                                    const float2* __restrict__ tabs,
                                                    const float* __restrict__ qw,
                                                    const float* __restrict__ kw,
                                                    ushort* __restrict__ qbf,
                                                    ushort* __restrict__ kbf) {
    int token = blockIdx.x;
    int lane = threadIdx.x & 63;
    int w = threadIdx.x >> 6;
    int t  = token / (HH * WW);
    int rem = token % (HH * WW);
    int xx = rem / WW;
    int yy = rem % WW;

    float2 cs = make_float2(1.f, 0.f);
    if (lane < 60) {
        int p = lane >> 1;
        int tr;
        if (p < 10)      tr = t * 10 + p;
        else if (p < 20) tr = (8 + xx) * 10 + (p - 10);
        else             tr = (56 + yy) * 10 + (p - 20);
        cs = tabs[tr];
    }
    float qwl = qw[lane], kwl = kw[lane];
#pragma unroll
    for (int hh = 0; hh < 2; ++hh) {
        int h = w * 2 + hh;
        const ushort* base = qkvb + (size_t)token * 1536 + h * 192;
        size_t ob = (size_t)token * 512 + h * 64 + lane;
#pragma unroll
        for (int qk = 0; qk < 2; ++qk) {
            float x = bf2f(base[qk * 64 + lane]);
            float ss = x * x;
#pragma unroll
            for (int o = 32; o; o >>= 1) ss += __shfl_xor(ss, o);
            float scale = rsqrtf(ss * (1.0f / 64.0f) + 1e-6f);
            float xn = x * scale * (qk ? kwl : qwl);
            float partner = __shfl_xor(xn, 1);
            float r = xn;
            if (lane < 60) {
                r = (lane & 1) ? fmaf(xn, cs.x,  partner * cs.y)
                               : fmaf(xn, cs.x, -partner * cs.y);
            }
            if (!qk) r *= 0.125f;   // fold HD^-0.5 into q (exact pow2)
            (qk ? kbf : qbf)[ob] = f2bf(r);
        }
    }
}

// ---------------- MFMA neighborhood attention: swapped operands,
// in-register lane-local masked softmax. Block = (2x2 patch, head).
// 32 q (8t x 2x2) x 128 k (8t x 4x4 window). V read in-place from qkvb.
__global__ __launch_bounds__(256) void attn_mfma(const ushort* __restrict__ qbf,
                                                 const ushort* __restrict__ kbf,
                                                 const ushort* __restrict__ qkvb,
                                                 ushort* __restrict__ ohi) {
    __shared__ __align__(16) char smem[45056];
    constexpr int Q_OFF = 0;       // [32 q][64 d] bf16, 128B rows, slot16 ^= row&7
    constexpr int K_OFF = 4096;    // [128 k][64 d] bf16, 128B rows, slot16 ^= row&7
    constexpr int V_OFF = 20480;   // [64 d][128 k] bf16, 256B rows, slot16 ^= d&7
    constexpr int P_OFF = 36864;   // [32 q][128 k] bf16, 256B rows, slot16 ^= q&7

    int patch = blockIdx.x, head = blockIdx.y;
    int bi = patch / 24, bj = patch % 24;
    int x0 = bi * 2, y0 = bj * 2;
    int ubx = min(max(x0 - 1, 0), 44), uby = min(max(y0 - 1, 0), 44);
    int tid = threadIdx.x, lane = tid & 63, w = tid >> 6;
    int fr = lane & 15, kg = lane >> 4;

    // ---- stage Q (1 gload/thread, pre-swizzled source chunk)
    {
        int f = tid;
        int row = f >> 3, sp = f & 7, sl = sp ^ (row & 7);
        int t = row >> 2, px = (row >> 1) & 1, py = row & 1;
        size_t tok = ((size_t)(t * HH + x0 + px)) * WW + (y0 + py);
        gload16(qbf + tok * 512 + head * 64 + sl * 8, smem + Q_OFF + f * 16);
    }
    // ---- stage K (4 gloads/thread)
#pragma unroll
    for (int it = 0; it < 4; ++it) {
        int f = it * 256 + tid;
        int row = f >> 3, sp = f & 7, sl = sp ^ (row & 7);
        int s = row >> 4, ki = (row >> 2) & 3, kj = row & 3;
        size_t tok = ((size_t)(s * HH + ubx + ki)) * WW + (uby + kj);
        gload16(kbf + tok * 512 + head * 64 + sl * 8, smem + K_OFF + f * 16);
    }
    // ---- stage V^T from qkvb (stride-1536 rows): register 4x4 transpose
#pragma unroll
    for (int it = 0; it < 2; ++it) {
        int u = it * 256 + tid;
        int sk = u >> 4, dg = u & 15;
        int s = sk >> 2, ki = sk & 3;
        ushort4 rv[4];
#pragma unroll
        for (int kj = 0; kj < 4; ++kj) {
            size_t tok = ((size_t)(s * HH + ubx + ki)) * WW + (uby + kj);
            rv[kj] = *(const ushort4*)(qkvb + tok * 1536 + head * 192 + 128 + dg * 4);
        }
        const ushort* rr = (const ushort*)rv;   // rr[kj*4 + dd]
#pragma unroll
        for (int dd = 0; dd < 4; ++dd) {
            int d = dg * 4 + dd;
            ushort4 val = {rr[dd], rr[4 + dd], rr[8 + dd], rr[12 + dd]};
            *(ushort4*)(smem + V_OFF + d * 256 + ((sk * 8) ^ ((d & 7) << 4))) = val;
        }
    }
    __syncthreads();

    // ---- QK^T swapped (S^T = K * Q^T) + in-register masked softmax: waves 0,1
    if (w < 2) {
        int q = w * 16 + fr;         // q = t*4 + px*2 + py
        bf16x8 qb[2];
#pragma unroll
        for (int ks = 0; ks < 2; ++ks)
            qb[ks] = *(const bf16x8*)(smem + Q_OFF + q * 128 +
                                      ((ks * 64 + kg * 16) ^ ((fr & 7) << 4)));
        f32x4 sc[8];
#pragma unroll
        for (int m = 0; m < 8; ++m) sc[m] = (f32x4){0.f, 0.f, 0.f, 0.f};
#pragma unroll
        for (int m = 0; m < 8; ++m)
#pragma unroll
            for (int ks = 0; ks < 2; ++ks) {
                bf16x8 a = *(const bf16x8*)(smem + K_OFF + (m * 16 + fr) * 128 +
                                            ((ks * 64 + kg * 16) ^ ((fr & 7) << 4)));
                sc[m] = mfma_bf16(a, qb[ks], sc[m]);
            }
        // lane holds S[k = m*16 + kg*4 + i][q]: s=m, ki=kg, kj=i
        int xq = x0 + ((q >> 1) & 1), yq = y0 + (q & 1);
        int lox = min(max(xq - 1, 0), 45) - ubx;
        int loy = min(max(yq - 1, 0), 45) - uby;
        bool vki = ((unsigned)(kg - lox)) <= 2u;
        float mx = -1e30f;
        if (vki) {
#pragma unroll
            for (int m = 0; m < 8; ++m)
#pragma unroll
                for (int i = 0; i < 4; ++i)
                    if (((unsigned)(i - loy)) <= 2u) mx = fmaxf(mx, sc[m][i]);
        }
        mx = fmaxf(mx, __shfl_xor(mx, 16));
        mx = fmaxf(mx, __shfl_xor(mx, 32));
        float sum = 0.f;
#pragma unroll
        for (int m = 0; m < 8; ++m)
#pragma unroll
            for (int i = 0; i < 4; ++i) {
                bool v = vki && (((unsigned)(i - loy)) <= 2u);
                float e = v ? __expf(sc[m][i] - mx) : 0.f;
                sc[m][i] = e;
                sum += e;
            }
        sum += __shfl_xor(sum, 16);
        sum += __shfl_xor(sum, 32);
        float inv = 1.0f / sum;
#pragma unroll
        for (int m = 0; m < 8; ++m) {
            ushort4 pk = {f2bf(sc[m][0] * inv), f2bf(sc[m][1] * inv),
                          f2bf(sc[m][2] * inv), f2bf(sc[m][3] * inv)};
            *(ushort4*)(smem + P_OFF + q * 256 +
                        ((m * 32 + kg * 8) ^ ((q & 7) << 4))) = pk;
        }
    }
    __syncthreads();

    // ---- PV swapped (out^T = V^T * P^T): wave w owns d-tile w
    f32x4 ov[2];
    ov[0] = (f32x4){0.f, 0.f, 0.f, 0.f};
    ov[1] = (f32x4){0.f, 0.f, 0.f, 0.f};
#pragma unroll
    for (int kb = 0; kb < 4; ++kb) {
        bf16x8 a = *(const bf16x8*)(smem + V_OFF + (w * 16 + fr) * 256 +
                                    ((kb * 64 + kg * 16) ^ ((fr & 7) << 4)));
#pragma unroll
        for (int nt2 = 0; nt2 < 2; ++nt2) {
            bf16x8 b = *(const bf16x8*)(smem + P_OFF + (nt2 * 16 + fr) * 256 +
                                        ((kb * 64 + kg * 16) ^ ((fr & 7) << 4)));
            ov[nt2] = mfma_bf16(a, b, ov[nt2]);
        }
    }
    // ---- epilogue: lane holds out^T[d = w*16+kg*4+i][q = nt2*16+fr]
#pragma unroll
    for (int nt2 = 0; nt2 < 2; ++nt2) {
        int q = nt2 * 16 + fr;
        int t = q >> 2, px = (q >> 1) & 1, py = q & 1;
        size_t tok = ((size_t)(t * HH + x0 + px)) * WW + (y0 + py);
        size_t ob = tok * 512 + head * 64 + w * 16 + kg * 4;
        ushort4 hv = {f2bf(ov[nt2][0]), f2bf(ov[nt2][1]),
                      f2bf(ov[nt2][2]), f2bf(ov[nt2][3])};
        *(ushort4*)&ohi[ob] = hv;
    }
}

extern "C" void kernel_launch(void* const* d_in, const int* in_sizes, int n_in,
                              void* d_out, int out_size, void* d_ws, size_t ws_size,
                              hipStream_t stream) {
    const float* x     = (const float*)d_in[0];
    const float* w_qkv = (const float*)d_in[1];
    const float* w_out = (const float*)d_in[2];
    const float* qnw   = (const float*)d_in[3];
    const float* knw   = (const float*)d_in[4];
    float* out = (float*)d_out;
    char*  ws  = (char*)d_ws;

    const size_t QKVB_B = (size_t)TOK * 1536 * 2;   // 56,623,104  (bf16 qkv)
    const size_t TABS_B = 16384;
    const size_t WQ_B   = (size_t)1536 * 512 * 2;   // 1,572,864
    const size_t WO_B   = (size_t)512 * 512 * 2;    //   524,288

    // ws layout: qkvb | tabs | wqhi | wohi | ohi
    ushort* qkvb = (ushort*)ws;
    float2* tabs = (float2*)(ws + QKVB_B);
    ushort* wqhi = (ushort*)(ws + QKVB_B + TABS_B);
    ushort* wohi = wqhi + (size_t)1536 * 512;
    ushort* ohi  = (ushort*)(ws + QKVB_B + TABS_B + WQ_B + WO_B);

    // d_out region (75.5 MB) multiplexed over time:
    //   phase 1: xhi (bf16 x, 37.7 MB)            [written by conv, read by gemm1]
    //   phase 2: qbf | kbf (2 x 18.9 MB = 75.5)   [overwrite xhi after gemm1]
    //   phase 3: final fp32 out                    [gemm2 overwrites everything]
    ushort* xhi = (ushort*)d_out;
    ushort* qbf = (ushort*)d_out;
    ushort* kbf = qbf + (size_t)TOK * 512;

    fill_tabs<<<5, 256, 0, stream>>>(tabs);
    conv_hi<<<(TOK * 512 / 4 + 255) / 256, 256, 0, stream>>>(x, xhi, TOK * 512 / 4);
    conv_hi<<<(1536 * 512 / 4 + 255) / 256, 256, 0, stream>>>(w_qkv, wqhi, 1536 * 512 / 4);
    conv_hi<<<(512 * 512 / 4 + 255) / 256, 256, 0, stream>>>(w_out, wohi, 512 * 512 / 4);

    // qkv(bf16) = x @ w_qkv^T
    gemm_mfma<1><<<(TOK / 128) * (1536 / 128), 256, 0, stream>>>(
        xhi, wqhi, qkvb, 1536, 512, 1536 / 128);
    norm_rope_v3<<<TOK, 256, 0, stream>>>(qkvb, tabs, qnw, knw, qbf, kbf);
    attn_mfma<<<dim3(576, NH), 256, 0, stream>>>(qbf, kbf, qkvb, ohi);
    // out(fp32) = o @ w_out^T
    gemm_mfma<0><<<(TOK / 128) * (512 / 128), 256, 0, stream>>>(
        ohi, wohi, out, 512, 512, 512 / 128);
}